// Round 1
// baseline (538.568 us; speedup 1.0000x reference)
//
#include <hip/hip_runtime.h>
#include <stdint.h>

#define CC 6
#define BB 4096
#define TT 512
#define HH 26
#define NSEQ (CC*BB)      // 24576
#define FF (CC*HH)        // 156

__device__ __forceinline__ float fast_exp2(float x) {
#if __has_builtin(__builtin_amdgcn_exp2f)
  return __builtin_amdgcn_exp2f(x);
#else
  return exp2f(x);
#endif
}
__device__ __forceinline__ float fast_rcp(float x) {
#if __has_builtin(__builtin_amdgcn_rcpf)
  return __builtin_amdgcn_rcpf(x);
#else
  return 1.0f / x;
#endif
}

// ---------------- sort-by-length (counting sort, longest first) ----------------

__global__ void zero_hist_kernel(unsigned int* hist, unsigned int* cursor) {
  hist[threadIdx.x] = 0u;
  cursor[threadIdx.x] = 0u;
}

__global__ void hist_kernel(const int* __restrict__ lengths, unsigned int* __restrict__ hist) {
  int s = blockIdx.x * 256 + threadIdx.x;       // 0..24575
  int c = s >> 12, b = s & 4095;
  int len = lengths[b * CC + c];                // 1..512
  atomicAdd(&hist[TT - len], 1u);               // bin 0 = longest
}

__global__ void scan_kernel(const unsigned int* __restrict__ hist, unsigned int* __restrict__ offs) {
  __shared__ unsigned int tmp[512];
  int t = threadIdx.x;
  tmp[t] = hist[t];
  __syncthreads();
  for (int d = 1; d < 512; d <<= 1) {
    unsigned int v = (t >= d) ? tmp[t - d] : 0u;
    __syncthreads();
    tmp[t] += v;
    __syncthreads();
  }
  offs[t] = tmp[t] - hist[t];                   // exclusive prefix
}

__global__ void scatter_kernel(const int* __restrict__ lengths, const unsigned int* __restrict__ offs,
                               unsigned int* __restrict__ cursor, unsigned int* __restrict__ perm) {
  int s = blockIdx.x * 256 + threadIdx.x;
  int c = s >> 12, b = s & 4095;
  int len = lengths[b * CC + c];
  int bin = TT - len;
  unsigned int pos = offs[bin] + atomicAdd(&cursor[bin], 1u);
  perm[pos] = (unsigned int)s;
}

// ---------------- RNN: 4 lanes per sequence, butterfly all-gather ----------------
// Lane sub owns padded rows sub*7..sub*7+6 (rows 26,27 are fake; lane3 slots 5,6
// carry x0,x1 so Wih folds into columns 26,27 of the combined weight).
// Column order per lane is butterfly order: blocks [sub, sub^1, sub^2, sub^3] of 7.

__global__ __launch_bounds__(64, 1) void rnn_kernel(
    const float* __restrict__ x, const int* __restrict__ lengths,
    const float* __restrict__ Wih, const float* __restrict__ Whh,
    const float* __restrict__ bih, const float* __restrict__ bhh,
    const unsigned int* __restrict__ perm, float* __restrict__ fbuf)
{
  const int lane = threadIdx.x;
  const int g = blockIdx.x * 16 + (lane >> 2);
  const int sub = lane & 3;
  const unsigned int s = perm[g];
  const int c = (int)(s >> 12);
  const int b = (int)(s & 4095u);
  const int len = lengths[b * CC + c];

  // wave max length (uniform loop bound)
  int ml = len;
#pragma unroll
  for (int m = 32; m >= 1; m >>= 1) {
    int o = __shfl_xor(ml, m);
    ml = ml > o ? ml : o;
  }

  const float S = 2.0f * 1.44269504088896340736f;  // 2*log2(e), prescale for exp2-tanh
  const int cb0 = sub * 7, cb1 = (sub ^ 1) * 7, cb2 = (sub ^ 2) * 7, cb3 = (sub ^ 3) * 7;
  const int rowbase = sub * 7;

  float w[7][28];
  float bias[7];
#pragma unroll
  for (int r = 0; r < 7; ++r) {
    int row = rowbase + r;
    bool rv = (row < HH);
    int rs = rv ? row : 0;
    const float* whrow = Whh + ((size_t)c * HH + rs) * HH;
    const float* wirow = Wih + ((size_t)c * HH + rs) * 2;
    bias[r] = rv ? S * (bih[c * HH + rs] + bhh[c * HH + rs]) : 0.f;
#pragma unroll
    for (int k = 0; k < 28; ++k) {
      int blk = k / 7;
      int col = (blk == 0 ? cb0 : blk == 1 ? cb1 : blk == 2 ? cb2 : cb3) + (k % 7);
      float wv = (col < HH) ? whrow[col] : wirow[col - HH];
      w[r][k] = rv ? S * wv : 0.f;
    }
  }

  float h[7];
#pragma unroll
  for (int r = 0; r < 7; ++r) h[r] = 0.f;

  const bool is3 = (sub == 3);
  const float* xp = x + (size_t)s * (TT * 2);

  float4 c0 = *reinterpret_cast<const float4*>(xp + (TT - 4) * 2);
  float4 c1 = *reinterpret_cast<const float4*>(xp + (TT - 4) * 2 + 4);
  const int nchunk = (ml + 3) >> 2;

  for (int cc = 0; cc < nchunk; ++cc) {
    float4 n0 = c0, n1 = c1;
    if (cc < 127) {  // prefetch next chunk (always in-bounds)
      const float* nxt = xp + (TT - 8 - 4 * cc) * 2;
      n0 = *reinterpret_cast<const float4*>(nxt);
      n1 = *reinterpret_cast<const float4*>(nxt + 4);
    }
    float xf[8] = {c0.x, c0.y, c0.z, c0.w, c1.x, c1.y, c1.z, c1.w};
#pragma unroll
    for (int j = 0; j < 4; ++j) {
      float xa = xf[(3 - j) * 2];
      float xb = xf[(3 - j) * 2 + 1];
      float ha[14];
#pragma unroll
      for (int k = 0; k < 5; ++k) ha[k] = h[k];
      ha[5] = is3 ? xa : h[5];
      ha[6] = is3 ? xb : h[6];
#pragma unroll
      for (int k = 0; k < 7; ++k) ha[7 + k] = __shfl_xor(ha[k], 1);
      float acc[7];
#pragma unroll
      for (int r = 0; r < 7; ++r) acc[r] = bias[r];
#pragma unroll
      for (int k = 0; k < 14; ++k)
#pragma unroll
        for (int r = 0; r < 7; ++r) acc[r] = fmaf(w[r][k], ha[k], acc[r]);
      float hb[14];
#pragma unroll
      for (int k = 0; k < 14; ++k) hb[k] = __shfl_xor(ha[k], 2);
#pragma unroll
      for (int k = 0; k < 14; ++k)
#pragma unroll
        for (int r = 0; r < 7; ++r) acc[r] = fmaf(w[r][14 + k], hb[k], acc[r]);
      const bool upd = (4 * cc + j) < len;
#pragma unroll
      for (int r = 0; r < 7; ++r) {
        float p = fast_exp2(acc[r]);
        float rc = fast_rcp(p + 1.0f);
        float hn = fmaf(-2.0f, rc, 1.0f);   // tanh(z), z prescaled into acc
        h[r] = upd ? hn : h[r];
      }
    }
    c0 = n0; c1 = n1;
  }

  // f[b, c*26 + i] = relu(hT[25 - i])  (H-axis reversal + relu)
  float* fb = fbuf + (size_t)b * FF + c * HH;
#pragma unroll
  for (int r = 0; r < 7; ++r) {
    int row = rowbase + r;
    if (row < HH) fb[25 - row] = fmaxf(h[r], 0.f);
  }
}

// ---------------- MLP ----------------

__global__ void mlp1_kernel(const float* __restrict__ fbuf, const float* __restrict__ W1,
                            const float* __restrict__ b1, float* __restrict__ h1buf) {
  __shared__ float fsh[32 * FF];
  int b0 = blockIdx.x * 32;
  for (int i = threadIdx.x; i < 32 * FF; i += 256) fsh[i] = fbuf[(size_t)b0 * FF + i];
  __syncthreads();
  int rr = threadIdx.x & 31;
  int ch = threadIdx.x >> 5;
  const float4* frow = reinterpret_cast<const float4*>(&fsh[rr * FF]);
  for (int j = ch; j < 300; j += 8) {
    const float4* wrow = reinterpret_cast<const float4*>(&W1[(size_t)j * FF]);
    float acc = b1[j];
#pragma unroll 4
    for (int k = 0; k < FF / 4; ++k) {
      float4 f = frow[k]; float4 wv = wrow[k];
      acc += f.x * wv.x + f.y * wv.y + f.z * wv.z + f.w * wv.w;
    }
    h1buf[(size_t)(b0 + rr) * 300 + j] = fmaxf(acc, 0.f);
  }
}

__global__ void mlp23_kernel(const float* __restrict__ h1buf, const float* __restrict__ W2,
                             const float* __restrict__ b2, const float* __restrict__ W3,
                             const float* __restrict__ b3, float* __restrict__ out) {
  __shared__ float h1sh[32 * 300];
  __shared__ float h2sh[32 * 50];
  int b0 = blockIdx.x * 32;
  for (int i = threadIdx.x; i < 32 * 300; i += 256) h1sh[i] = h1buf[(size_t)b0 * 300 + i];
  __syncthreads();
  int rr = threadIdx.x & 31;
  int ch = threadIdx.x >> 5;
  const float4* hrow = reinterpret_cast<const float4*>(&h1sh[rr * 300]);
  for (int j = ch; j < 50; j += 8) {
    const float4* wrow = reinterpret_cast<const float4*>(&W2[(size_t)j * 300]);
    float acc = b2[j];
#pragma unroll 4
    for (int k = 0; k < 75; ++k) {
      float4 h = hrow[k]; float4 wv = wrow[k];
      acc += h.x * wv.x + h.y * wv.y + h.z * wv.z + h.w * wv.w;
    }
    h2sh[rr * 50 + j] = fmaxf(acc, 0.f);
  }
  __syncthreads();
  for (int idx = threadIdx.x; idx < 32 * 14; idx += 256) {
    int r2 = idx / 14;
    int j = idx - r2 * 14;
    float acc = b3[j];
    const float* h2 = &h2sh[r2 * 50];
    const float* wv = &W3[(size_t)j * 50];
#pragma unroll
    for (int k = 0; k < 50; ++k) acc += h2[k] * wv[k];
    out[(size_t)(b0 + r2) * 14 + j] = fmaxf(acc, 0.f);
  }
}

// ---------------- launch ----------------

extern "C" void kernel_launch(void* const* d_in, const int* in_sizes, int n_in,
                              void* d_out, int out_size, void* d_ws, size_t ws_size,
                              hipStream_t stream) {
  (void)in_sizes; (void)n_in; (void)out_size; (void)ws_size;
  const float* x       = (const float*)d_in[0];
  const int*   lengths = (const int*)  d_in[1];
  const float* Wih     = (const float*)d_in[2];
  const float* Whh     = (const float*)d_in[3];
  const float* bih     = (const float*)d_in[4];
  const float* bhh     = (const float*)d_in[5];
  const float* W1      = (const float*)d_in[6];
  const float* b1      = (const float*)d_in[7];
  const float* W2      = (const float*)d_in[8];
  const float* b2      = (const float*)d_in[9];
  const float* W3      = (const float*)d_in[10];
  const float* b3      = (const float*)d_in[11];
  float* out = (float*)d_out;

  unsigned int* hist   = (unsigned int*)d_ws;
  unsigned int* cursor = hist + 512;
  unsigned int* offs   = cursor + 512;
  unsigned int* perm   = offs + 512;
  float* fbuf  = (float*)(perm + NSEQ);
  float* h1buf = fbuf + (size_t)BB * FF;

  zero_hist_kernel<<<1, 512, 0, stream>>>(hist, cursor);
  hist_kernel<<<NSEQ / 256, 256, 0, stream>>>(lengths, hist);
  scan_kernel<<<1, 512, 0, stream>>>(hist, offs);
  scatter_kernel<<<NSEQ / 256, 256, 0, stream>>>(lengths, offs, cursor, perm);
  rnn_kernel<<<NSEQ * 4 / 64, 64, 0, stream>>>(x, lengths, Wih, Whh, bih, bhh, perm, fbuf);
  mlp1_kernel<<<BB / 32, 256, 0, stream>>>(fbuf, W1, b1, h1buf);
  mlp23_kernel<<<BB / 32, 256, 0, stream>>>(h1buf, W2, b2, W3, b3, out);
}

// Round 2
// 369.630 us; speedup vs baseline: 1.4570x; 1.4570x over previous
//
#include <hip/hip_runtime.h>
#include <stdint.h>

#define CC 6
#define BB 4096
#define TT 512
#define HH 26
#define NSEQ (CC*BB)      // 24576
#define FF (CC*HH)        // 156
#define NBIN (CC*TT)      // 3072

typedef _Float16 f16x8 __attribute__((ext_vector_type(8)));
typedef _Float16 f16x2 __attribute__((ext_vector_type(2)));
typedef float    f32x4 __attribute__((ext_vector_type(4)));
typedef int      i32x4 __attribute__((ext_vector_type(4)));

__device__ __forceinline__ float fast_exp2(float x){ return __builtin_amdgcn_exp2f(x); }
__device__ __forceinline__ float fast_rcp(float x){ return __builtin_amdgcn_rcpf(x); }
// tanh(z) with z prescaled by 2*log2(e): 1 - 2/(exp2(z')+1)
__device__ __forceinline__ float th(float a){ return fmaf(-2.f, fast_rcp(fast_exp2(a)+1.f), 1.f); }
__device__ __forceinline__ int pkf16(float a, float b){
  return __builtin_bit_cast(int, __builtin_amdgcn_cvt_pkrtz(a, b));
}

// ---------------- fused counting sort: key = c*512 + (512-len), longest first per channel ----------------
// One block, 1024 threads. Each channel owns exactly 4096 slots of perm -> waves never straddle channels.

__global__ __launch_bounds__(1024) void sort_kernel(const int* __restrict__ lengths,
                                                    unsigned int* __restrict__ perm) {
  __shared__ unsigned int hist[NBIN];
  __shared__ unsigned int curs[NBIN];
  __shared__ unsigned int tmp[1024];
  const int t = threadIdx.x;
  for (int i = t; i < NBIN; i += 1024) hist[i] = 0u;
  __syncthreads();
#pragma unroll
  for (int i = 0; i < 24; ++i) {
    int s = t + i * 1024;
    int c = s >> 12, b = s & 4095;
    int len = lengths[b * CC + c];               // 1..512
    atomicAdd(&hist[(c << 9) | (TT - len)], 1u);
  }
  __syncthreads();
  unsigned a0 = hist[3*t], a1 = hist[3*t+1], a2 = hist[3*t+2];
  unsigned ts = a0 + a1 + a2;
  tmp[t] = ts;
  __syncthreads();
  for (int d = 1; d < 1024; d <<= 1) {
    unsigned v = (t >= d) ? tmp[t - d] : 0u;
    __syncthreads();
    tmp[t] += v;
    __syncthreads();
  }
  unsigned excl = tmp[t] - ts;
  hist[3*t]   = excl;
  hist[3*t+1] = excl + a0;
  hist[3*t+2] = excl + a0 + a1;
  curs[3*t] = 0u; curs[3*t+1] = 0u; curs[3*t+2] = 0u;
  __syncthreads();
#pragma unroll
  for (int i = 0; i < 24; ++i) {
    int s = t + i * 1024;
    int c = s >> 12, b = s & 4095;
    int len = lengths[b * CC + c];
    int bin = (c << 9) | (TT - len);
    unsigned p = atomicAdd(&curs[bin], 1u);
    perm[hist[bin] + p] = (unsigned)s;
  }
}

// ---------------- RNN: one wave = 16 same-channel sequences, MFMA f16 recurrence ----------------
// D[m=out-row 0..25][n=seq 0..15] = W'(26x28) * h_ext(28x16) + bias, two 16x16x32 MFMAs (m 0-15, 16-31).
// W' = [Whh | Wih] scaled by 2*log2(e); h_ext k=0..25 = h, k=26,27 = x_t, k=28..31 = 0.
// A frag: lane l: m=l&15, k=8*(l>>4)+j.  B frag: n=l&15, k=8*(l>>4)+j.  D: n=l&15, m=4*(l>>4)+reg.

__global__ __launch_bounds__(64) void rnn_kernel(
    const float* __restrict__ x, const int* __restrict__ lengths,
    const float* __restrict__ Wih, const float* __restrict__ Whh,
    const float* __restrict__ bih, const float* __restrict__ bhh,
    const unsigned int* __restrict__ perm, float* __restrict__ fbuf)
{
  const int l   = threadIdx.x;
  const int col = l & 15;      // sequence slot
  const int grp = l >> 4;      // k-group / m-group
  const int g   = blockIdx.x;
  const unsigned s = perm[g * 16 + col];
  const int c = (int)(s >> 12);
  const int b = (int)(s & 4095u);
  const int lenc = lengths[b * CC + c];

  int ml = lenc;                         // wave max length (cols repeat every 16 lanes)
#pragma unroll
  for (int m = 8; m >= 1; m >>= 1) { int o = __shfl_xor(ml, m); ml = ml > o ? ml : o; }

  const float S = 2.0f * 1.44269504088896340736f;
  const float* WhhC = Whh + (size_t)c * HH * HH;
  const float* WihC = Wih + (size_t)c * HH * 2;

  f16x8 A1, A2;
#pragma unroll
  for (int j = 0; j < 8; ++j) {
    int k = grp * 8 + j;
    float v1 = (k < HH) ? WhhC[col * HH + k] : ((k < HH + 2) ? WihC[col * 2 + (k - HH)] : 0.f);
    A1[j] = (_Float16)(S * v1);
    int m2 = 16 + col;
    float v2 = 0.f;
    if (m2 < HH) v2 = (k < HH) ? WhhC[m2 * HH + k] : ((k < HH + 2) ? WihC[m2 * 2 + (k - HH)] : 0.f);
    A2[j] = (_Float16)(S * v2);
  }
  f32x4 Cb1, Cb2;
#pragma unroll
  for (int i = 0; i < 4; ++i) {
    int m1 = grp * 4 + i;
    Cb1[i] = S * (bih[c * HH + m1] + bhh[c * HH + m1]);
    int m2 = 16 + grp * 4 + i;
    Cb2[i] = (m2 < HH) ? S * (bih[c * HH + m2] + bhh[c * HH + m2]) : 0.f;
  }

  // B state regs (packed f16 pairs): lane holds k = 8*grp + {0..7} of its col's h_ext
  int b0 = 0, b1v = 0, b2v = 0, b3v = 0;
  const bool isg3 = (grp == 3);
  const float* xp = x + (size_t)s * (TT * 2);

  float4 c0 = make_float4(0.f, 0.f, 0.f, 0.f), c1 = c0;
  if (isg3) {
    c0 = *(const float4*)(xp + (TT - 4) * 2);
    c1 = *(const float4*)(xp + (TT - 4) * 2 + 4);
  }
  const int srcA = col + ((grp & 1) ? 32 : 0);
  const int srcB = srcA + 16;
  const bool lo = (grp < 2);
  const int nch = (ml + 3) >> 2;

  for (int cc = 0; cc < nch; ++cc) {
    float4 n0 = c0, n1 = c1;
    if (isg3 && cc < 127) {
      const float* nxt = xp + (TT - 8 - 4 * cc) * 2;
      n0 = *(const float4*)nxt;
      n1 = *(const float4*)(nxt + 4);
    }
    float xf[8] = {c0.x, c0.y, c0.z, c0.w, c1.x, c1.y, c1.z, c1.w};
#pragma unroll
    for (int j = 0; j < 4; ++j) {
      const int t = 4 * cc + j;
      // splice x_t (k=26,27) and zero pad (k=28..31) into g3's B regs
      int pkx = pkf16(xf[(3 - j) * 2], xf[(3 - j) * 2 + 1]);
      if (isg3) { b1v = pkx; b2v = 0; b3v = 0; }
      i32x4 bi = {b0, b1v, b2v, b3v};
      f16x8 Bf = __builtin_bit_cast(f16x8, bi);
      f32x4 D1 = __builtin_amdgcn_mfma_f32_16x16x32_f16(A1, Bf, Cb1, 0, 0, 0);
      f32x4 D2 = __builtin_amdgcn_mfma_f32_16x16x32_f16(A2, Bf, Cb2, 0, 0, 0);
      // tanh + pack: q0* = m (4*grp, 4*grp+1),(+2,+3); q1* = +16
      int q00 = pkf16(th(D1[0]), th(D1[1]));
      int q01 = pkf16(th(D1[2]), th(D1[3]));
      int q10 = pkf16(th(D2[0]), th(D2[1]));
      int q11 = pkf16(th(D2[2]), th(D2[3]));
      // permute D-layout -> B-layout
      int t00 = __shfl(q00, srcA), t01 = __shfl(q01, srcA);
      int t10 = __shfl(q10, srcA), t11 = __shfl(q11, srcA);
      int u00 = __shfl(q00, srcB), u01 = __shfl(q01, srcB);
      int u10 = __shfl(q10, srcB), u11 = __shfl(q11, srcB);
      int nb0 = lo ? t00 : t10;
      int nb1 = lo ? t01 : t11;
      int nb2 = lo ? u00 : u10;
      int nb3 = lo ? u01 : u11;
      const bool upd = (t < lenc);
      b0  = upd ? nb0 : b0;
      b1v = upd ? nb1 : b1v;
      b2v = upd ? nb2 : b2v;
      b3v = upd ? nb3 : b3v;
    }
    c0 = n0; c1 = n1;
  }

  // epilogue: B holds h_T in f16 pairs; f[b, c*26 + (25-m)] = relu(h[m])
  float* fb = fbuf + (size_t)b * FF + c * HH;
  const int m0 = grp * 8;
  {
    f16x2 p;
    p = __builtin_bit_cast(f16x2, b0);
    if (m0 + 0 < HH) fb[25 - (m0 + 0)] = fmaxf((float)p[0], 0.f);
    if (m0 + 1 < HH) fb[25 - (m0 + 1)] = fmaxf((float)p[1], 0.f);
    p = __builtin_bit_cast(f16x2, b1v);
    if (m0 + 2 < HH) fb[25 - (m0 + 2)] = fmaxf((float)p[0], 0.f);
    if (m0 + 3 < HH) fb[25 - (m0 + 3)] = fmaxf((float)p[1], 0.f);
    p = __builtin_bit_cast(f16x2, b2v);
    if (m0 + 4 < HH) fb[25 - (m0 + 4)] = fmaxf((float)p[0], 0.f);
    if (m0 + 5 < HH) fb[25 - (m0 + 5)] = fmaxf((float)p[1], 0.f);
    p = __builtin_bit_cast(f16x2, b3v);
    if (m0 + 6 < HH) fb[25 - (m0 + 6)] = fmaxf((float)p[0], 0.f);
    if (m0 + 7 < HH) fb[25 - (m0 + 7)] = fmaxf((float)p[1], 0.f);
  }
}

// ---------------- fused 3-layer MLP ----------------

__global__ __launch_bounds__(256) void mlp_kernel(
    const float* __restrict__ fbuf,
    const float* __restrict__ W1, const float* __restrict__ b1p,
    const float* __restrict__ W2, const float* __restrict__ b2p,
    const float* __restrict__ W3, const float* __restrict__ b3p,
    float* __restrict__ out)
{
  __shared__ float fsh[32 * FF];
  __shared__ float h1sh[32 * 300];
  __shared__ float h2sh[32 * 50];
  const int base = blockIdx.x * 32;
  for (int i = threadIdx.x; i < 32 * FF; i += 256) fsh[i] = fbuf[(size_t)base * FF + i];
  __syncthreads();
  const int rr = threadIdx.x & 31;
  const int ch = threadIdx.x >> 5;
  const float4* frow = (const float4*)&fsh[rr * FF];
  for (int j = ch; j < 300; j += 8) {
    const float4* wrow = (const float4*)&W1[(size_t)j * FF];
    float acc = b1p[j];
#pragma unroll 4
    for (int k = 0; k < FF / 4; ++k) {
      float4 f = frow[k]; float4 w = wrow[k];
      acc += f.x * w.x + f.y * w.y + f.z * w.z + f.w * w.w;
    }
    h1sh[rr * 300 + j] = fmaxf(acc, 0.f);
  }
  __syncthreads();
  const float4* hrow = (const float4*)&h1sh[rr * 300];
  for (int j = ch; j < 50; j += 8) {
    const float4* wrow = (const float4*)&W2[(size_t)j * 300];
    float acc = b2p[j];
#pragma unroll 4
    for (int k = 0; k < 75; ++k) {
      float4 h = hrow[k]; float4 w = wrow[k];
      acc += h.x * w.x + h.y * w.y + h.z * w.z + h.w * w.w;
    }
    h2sh[rr * 50 + j] = fmaxf(acc, 0.f);
  }
  __syncthreads();
  for (int idx = threadIdx.x; idx < 32 * 14; idx += 256) {
    int r2 = idx / 14;
    int j = idx - r2 * 14;
    float acc = b3p[j];
    const float* h2 = &h2sh[r2 * 50];
    const float* wv = &W3[(size_t)j * 50];
#pragma unroll
    for (int k = 0; k < 50; ++k) acc += h2[k] * wv[k];
    out[(size_t)(base + r2) * 14 + j] = fmaxf(acc, 0.f);
  }
}

// ---------------- launch ----------------

extern "C" void kernel_launch(void* const* d_in, const int* in_sizes, int n_in,
                              void* d_out, int out_size, void* d_ws, size_t ws_size,
                              hipStream_t stream) {
  (void)in_sizes; (void)n_in; (void)out_size; (void)ws_size;
  const float* x       = (const float*)d_in[0];
  const int*   lengths = (const int*)  d_in[1];
  const float* Wih     = (const float*)d_in[2];
  const float* Whh     = (const float*)d_in[3];
  const float* bih     = (const float*)d_in[4];
  const float* bhh     = (const float*)d_in[5];
  const float* W1      = (const float*)d_in[6];
  const float* b1      = (const float*)d_in[7];
  const float* W2      = (const float*)d_in[8];
  const float* b2      = (const float*)d_in[9];
  const float* W3      = (const float*)d_in[10];
  const float* b3      = (const float*)d_in[11];
  float* out = (float*)d_out;

  unsigned int* perm = (unsigned int*)d_ws;
  float* fbuf = (float*)(perm + NSEQ);

  sort_kernel<<<1, 1024, 0, stream>>>(lengths, perm);
  rnn_kernel<<<NSEQ / 16, 64, 0, stream>>>(x, lengths, Wih, Whh, bih, bhh, perm, fbuf);
  mlp_kernel<<<BB / 32, 256, 0, stream>>>(fbuf, W1, b1, W2, b2, W3, b3, out);
}

// Round 3
// 289.771 us; speedup vs baseline: 1.8586x; 1.2756x over previous
//
#include <hip/hip_runtime.h>
#include <stdint.h>

#define CC 6
#define BB 4096
#define TT 512
#define HH 26
#define NSEQ (CC*BB)      // 24576
#define FF (CC*HH)        // 156
#define NBIN (CC*TT)      // 3072

typedef _Float16 f16x8 __attribute__((ext_vector_type(8)));
typedef _Float16 f16x2 __attribute__((ext_vector_type(2)));
typedef float    f32x4 __attribute__((ext_vector_type(4)));
typedef int      i32x4 __attribute__((ext_vector_type(4)));

__device__ __forceinline__ float fast_exp2(float x){ return __builtin_amdgcn_exp2f(x); }
__device__ __forceinline__ float fast_rcp(float x){ return __builtin_amdgcn_rcpf(x); }
// tanh(z) with z prescaled by 2*log2(e): 1 - 2/(exp2(z')+1)
__device__ __forceinline__ float th(float a){ return fmaf(-2.f, fast_rcp(fast_exp2(a)+1.f), 1.f); }
__device__ __forceinline__ int pkf16(float a, float b){
  return __builtin_bit_cast(int, __builtin_amdgcn_cvt_pkrtz(a, b));
}

// ---------------- fused counting sort: key = c*512 + (512-len), longest first per channel ----------------

__global__ __launch_bounds__(1024) void sort_kernel(const int* __restrict__ lengths,
                                                    unsigned int* __restrict__ perm) {
  __shared__ unsigned int hist[NBIN];
  __shared__ unsigned int curs[NBIN];
  __shared__ unsigned int tmp[1024];
  const int t = threadIdx.x;
  for (int i = t; i < NBIN; i += 1024) hist[i] = 0u;
  __syncthreads();
#pragma unroll
  for (int i = 0; i < 24; ++i) {
    int s = t + i * 1024;
    int c = s >> 12, b = s & 4095;
    int len = lengths[b * CC + c];               // 1..512
    atomicAdd(&hist[(c << 9) | (TT - len)], 1u);
  }
  __syncthreads();
  unsigned a0 = hist[3*t], a1 = hist[3*t+1], a2 = hist[3*t+2];
  unsigned ts = a0 + a1 + a2;
  tmp[t] = ts;
  __syncthreads();
  for (int d = 1; d < 1024; d <<= 1) {
    unsigned v = (t >= d) ? tmp[t - d] : 0u;
    __syncthreads();
    tmp[t] += v;
    __syncthreads();
  }
  unsigned excl = tmp[t] - ts;
  hist[3*t]   = excl;
  hist[3*t+1] = excl + a0;
  hist[3*t+2] = excl + a0 + a1;
  curs[3*t] = 0u; curs[3*t+1] = 0u; curs[3*t+2] = 0u;
  __syncthreads();
#pragma unroll
  for (int i = 0; i < 24; ++i) {
    int s = t + i * 1024;
    int c = s >> 12, b = s & 4095;
    int len = lengths[b * CC + c];
    int bin = (c << 9) | (TT - len);
    unsigned p = atomicAdd(&curs[bin], 1u);
    perm[hist[bin] + p] = (unsigned)s;
  }
}

// ---------------- RNN: one wave = TWO independent 16-seq MFMA streams (same channel) ----------------
// Per stream: D[26x16] = W'(26x28) * h_ext(28x16) + bias via two 16x16x32 f16 MFMAs.
// A frag: lane l: m=l&15, k=8*(l>>4)+j.  B frag: n=l&15, k=8*(l>>4)+j.  D: n=l&15, m=4*(l>>4)+reg.
// h_ext k=0..25 = h, k=26,27 = x_t (g3 lanes), k=28..31 = 0.

__global__ __launch_bounds__(64) void rnn_kernel(
    const float* __restrict__ x, const int* __restrict__ lengths,
    const float* __restrict__ Wih, const float* __restrict__ Whh,
    const float* __restrict__ bih, const float* __restrict__ bhh,
    const unsigned int* __restrict__ perm, float* __restrict__ fbuf)
{
  const int l   = threadIdx.x;
  const int col = l & 15;
  const int grp = l >> 4;
  const int g   = blockIdx.x;                    // 0..767
  const unsigned s0 = perm[g * 32 + col];
  const unsigned s1 = perm[g * 32 + 16 + col];
  const int c   = (int)(s0 >> 12);               // both streams same channel
  const int bi0 = (int)(s0 & 4095u);
  const int bi1 = (int)(s1 & 4095u);
  const int len0 = lengths[bi0 * CC + c];
  const int len1 = lengths[bi1 * CC + c];

  int ml = len0 > len1 ? len0 : len1;
#pragma unroll
  for (int m = 8; m >= 1; m >>= 1) { int o = __shfl_xor(ml, m); ml = ml > o ? ml : o; }

  const float S = 2.0f * 1.44269504088896340736f;
  const float* WhhC = Whh + (size_t)c * HH * HH;
  const float* WihC = Wih + (size_t)c * HH * 2;

  f16x8 A1, A2;
#pragma unroll
  for (int j = 0; j < 8; ++j) {
    int k = grp * 8 + j;
    float v1 = (k < HH) ? WhhC[col * HH + k] : ((k < HH + 2) ? WihC[col * 2 + (k - HH)] : 0.f);
    A1[j] = (_Float16)(S * v1);
    int m2 = 16 + col;
    float v2 = 0.f;
    if (m2 < HH) v2 = (k < HH) ? WhhC[m2 * HH + k] : ((k < HH + 2) ? WihC[m2 * 2 + (k - HH)] : 0.f);
    A2[j] = (_Float16)(S * v2);
  }
  f32x4 Cb1, Cb2;
#pragma unroll
  for (int i = 0; i < 4; ++i) {
    int m1 = grp * 4 + i;
    Cb1[i] = S * (bih[c * HH + m1] + bhh[c * HH + m1]);
    int m2 = 16 + grp * 4 + i;
    Cb2[i] = (m2 < HH) ? S * (bih[c * HH + m2] + bhh[c * HH + m2]) : 0.f;
  }

  // B state regs per stream
  int p0_0 = 0, p1_0 = 0, p2_0 = 0, p3_0 = 0;
  int p0_1 = 0, p1_1 = 0, p2_1 = 0, p3_1 = 0;
  const bool isg3 = (grp == 3);
  const float* xp0 = x + (size_t)s0 * (TT * 2);
  const float* xp1 = x + (size_t)s1 * (TT * 2);

  float4 a0 = make_float4(0,0,0,0), a1v = a0, e0 = a0, e1 = a0;
  if (isg3) {
    a0  = *(const float4*)(xp0 + (TT - 4) * 2);
    a1v = *(const float4*)(xp0 + (TT - 4) * 2 + 4);
    e0  = *(const float4*)(xp1 + (TT - 4) * 2);
    e1  = *(const float4*)(xp1 + (TT - 4) * 2 + 4);
  }
  const int srcA = col + ((grp & 1) ? 32 : 0);
  const int srcB = srcA + 16;
  const bool lo = (grp < 2);
  const int nch = (ml + 3) >> 2;

  for (int cc = 0; cc < nch; ++cc) {
    float4 na0 = a0, na1 = a1v, ne0 = e0, ne1 = e1;
    if (isg3 && cc < 127) {
      const float* nx0 = xp0 + (TT - 8 - 4 * cc) * 2;
      const float* nx1 = xp1 + (TT - 8 - 4 * cc) * 2;
      na0 = *(const float4*)nx0;  na1 = *(const float4*)(nx0 + 4);
      ne0 = *(const float4*)nx1;  ne1 = *(const float4*)(nx1 + 4);
    }
    float xf0[8] = {a0.x, a0.y, a0.z, a0.w, a1v.x, a1v.y, a1v.z, a1v.w};
    float xf1[8] = {e0.x, e0.y, e0.z, e0.w, e1.x, e1.y, e1.z, e1.w};
#pragma unroll
    for (int j = 0; j < 4; ++j) {
      const int t = 4 * cc + j;
      int px0 = pkf16(xf0[(3 - j) * 2], xf0[(3 - j) * 2 + 1]);
      int px1 = pkf16(xf1[(3 - j) * 2], xf1[(3 - j) * 2 + 1]);
      if (isg3) { p1_0 = px0; p2_0 = 0; p3_0 = 0; p1_1 = px1; p2_1 = 0; p3_1 = 0; }
      i32x4 bv0 = {p0_0, p1_0, p2_0, p3_0};
      i32x4 bv1 = {p0_1, p1_1, p2_1, p3_1};
      f16x8 B0 = __builtin_bit_cast(f16x8, bv0);
      f16x8 B1 = __builtin_bit_cast(f16x8, bv1);
      f32x4 D10 = __builtin_amdgcn_mfma_f32_16x16x32_f16(A1, B0, Cb1, 0, 0, 0);
      f32x4 D20 = __builtin_amdgcn_mfma_f32_16x16x32_f16(A2, B0, Cb2, 0, 0, 0);
      f32x4 D11 = __builtin_amdgcn_mfma_f32_16x16x32_f16(A1, B1, Cb1, 0, 0, 0);
      f32x4 D21 = __builtin_amdgcn_mfma_f32_16x16x32_f16(A2, B1, Cb2, 0, 0, 0);
      // tanh + pack (per stream)
      int q00_0 = pkf16(th(D10[0]), th(D10[1]));
      int q01_0 = pkf16(th(D10[2]), th(D10[3]));
      int q10_0 = pkf16(th(D20[0]), th(D20[1]));
      int q11_0 = pkf16(th(D20[2]), th(D20[3]));
      int q00_1 = pkf16(th(D11[0]), th(D11[1]));
      int q01_1 = pkf16(th(D11[2]), th(D11[3]));
      int q10_1 = pkf16(th(D21[0]), th(D21[1]));
      int q11_1 = pkf16(th(D21[2]), th(D21[3]));
      // D-layout -> B-layout permute (per stream)
      int t00_0 = __shfl(q00_0, srcA), t01_0 = __shfl(q01_0, srcA);
      int t10_0 = __shfl(q10_0, srcA), t11_0 = __shfl(q11_0, srcA);
      int u00_0 = __shfl(q00_0, srcB), u01_0 = __shfl(q01_0, srcB);
      int u10_0 = __shfl(q10_0, srcB), u11_0 = __shfl(q11_0, srcB);
      int t00_1 = __shfl(q00_1, srcA), t01_1 = __shfl(q01_1, srcA);
      int t10_1 = __shfl(q10_1, srcA), t11_1 = __shfl(q11_1, srcA);
      int u00_1 = __shfl(q00_1, srcB), u01_1 = __shfl(q01_1, srcB);
      int u10_1 = __shfl(q10_1, srcB), u11_1 = __shfl(q11_1, srcB);
      int n0_0 = lo ? t00_0 : t10_0;
      int n1_0 = lo ? t01_0 : t11_0;
      int n2_0 = lo ? u00_0 : u10_0;
      int n3_0 = lo ? u01_0 : u11_0;
      int n0_1 = lo ? t00_1 : t10_1;
      int n1_1 = lo ? t01_1 : t11_1;
      int n2_1 = lo ? u00_1 : u10_1;
      int n3_1 = lo ? u01_1 : u11_1;
      const bool u0 = (t < len0);
      const bool u1 = (t < len1);
      p0_0 = u0 ? n0_0 : p0_0;  p1_0 = u0 ? n1_0 : p1_0;
      p2_0 = u0 ? n2_0 : p2_0;  p3_0 = u0 ? n3_0 : p3_0;
      p0_1 = u1 ? n0_1 : p0_1;  p1_1 = u1 ? n1_1 : p1_1;
      p2_1 = u1 ? n2_1 : p2_1;  p3_1 = u1 ? n3_1 : p3_1;
    }
    a0 = na0; a1v = na1; e0 = ne0; e1 = ne1;
  }

  // epilogue: f[b, c*26 + (25-m)] = relu(h[m]) for both streams
  const int m0 = grp * 8;
  {
    float* fb = fbuf + (size_t)bi0 * FF + c * HH;
    f16x2 p;
    p = __builtin_bit_cast(f16x2, p0_0);
    if (m0 + 0 < HH) fb[25 - (m0 + 0)] = fmaxf((float)p[0], 0.f);
    if (m0 + 1 < HH) fb[25 - (m0 + 1)] = fmaxf((float)p[1], 0.f);
    p = __builtin_bit_cast(f16x2, p1_0);
    if (m0 + 2 < HH) fb[25 - (m0 + 2)] = fmaxf((float)p[0], 0.f);
    if (m0 + 3 < HH) fb[25 - (m0 + 3)] = fmaxf((float)p[1], 0.f);
    p = __builtin_bit_cast(f16x2, p2_0);
    if (m0 + 4 < HH) fb[25 - (m0 + 4)] = fmaxf((float)p[0], 0.f);
    if (m0 + 5 < HH) fb[25 - (m0 + 5)] = fmaxf((float)p[1], 0.f);
    p = __builtin_bit_cast(f16x2, p3_0);
    if (m0 + 6 < HH) fb[25 - (m0 + 6)] = fmaxf((float)p[0], 0.f);
    if (m0 + 7 < HH) fb[25 - (m0 + 7)] = fmaxf((float)p[1], 0.f);
  }
  {
    float* fb = fbuf + (size_t)bi1 * FF + c * HH;
    f16x2 p;
    p = __builtin_bit_cast(f16x2, p0_1);
    if (m0 + 0 < HH) fb[25 - (m0 + 0)] = fmaxf((float)p[0], 0.f);
    if (m0 + 1 < HH) fb[25 - (m0 + 1)] = fmaxf((float)p[1], 0.f);
    p = __builtin_bit_cast(f16x2, p1_1);
    if (m0 + 2 < HH) fb[25 - (m0 + 2)] = fmaxf((float)p[0], 0.f);
    if (m0 + 3 < HH) fb[25 - (m0 + 3)] = fmaxf((float)p[1], 0.f);
    p = __builtin_bit_cast(f16x2, p2_1);
    if (m0 + 4 < HH) fb[25 - (m0 + 4)] = fmaxf((float)p[0], 0.f);
    if (m0 + 5 < HH) fb[25 - (m0 + 5)] = fmaxf((float)p[1], 0.f);
    p = __builtin_bit_cast(f16x2, p3_1);
    if (m0 + 6 < HH) fb[25 - (m0 + 6)] = fmaxf((float)p[0], 0.f);
    if (m0 + 7 < HH) fb[25 - (m0 + 7)] = fmaxf((float)p[1], 0.f);
  }
}

// ---------------- fused 3-layer MLP: 8 rows/block, 512 blocks ----------------

__global__ __launch_bounds__(256) void mlp_kernel(
    const float* __restrict__ fbuf,
    const float* __restrict__ W1, const float* __restrict__ b1p,
    const float* __restrict__ W2, const float* __restrict__ b2p,
    const float* __restrict__ W3, const float* __restrict__ b3p,
    float* __restrict__ out)
{
  __shared__ float fsh[8 * FF];
  __shared__ float h1sh[8 * 300];
  __shared__ float h2sh[8 * 50];
  const int base = blockIdx.x * 8;
  for (int i = threadIdx.x; i < 8 * FF; i += 256) fsh[i] = fbuf[(size_t)base * FF + i];
  __syncthreads();
  const int rr = threadIdx.x & 7;
  const int ch = threadIdx.x >> 3;               // 0..31
  const float4* frow = (const float4*)&fsh[rr * FF];
  for (int j = ch; j < 300; j += 32) {
    const float4* wrow = (const float4*)&W1[(size_t)j * FF];
    float ax = 0.f, ay = 0.f, az = 0.f, aw = 0.f;
#pragma unroll 13
    for (int k = 0; k < FF / 4; ++k) {
      float4 f = frow[k]; float4 w = wrow[k];
      ax = fmaf(f.x, w.x, ax); ay = fmaf(f.y, w.y, ay);
      az = fmaf(f.z, w.z, az); aw = fmaf(f.w, w.w, aw);
    }
    h1sh[rr * 300 + j] = fmaxf(b1p[j] + (ax + ay) + (az + aw), 0.f);
  }
  __syncthreads();
  const float4* hrow = (const float4*)&h1sh[rr * 300];
  for (int j = ch; j < 50; j += 32) {
    const float4* wrow = (const float4*)&W2[(size_t)j * 300];
    float ax = 0.f, ay = 0.f, az = 0.f, aw = 0.f;
#pragma unroll 15
    for (int k = 0; k < 75; ++k) {
      float4 h = hrow[k]; float4 w = wrow[k];
      ax = fmaf(h.x, w.x, ax); ay = fmaf(h.y, w.y, ay);
      az = fmaf(h.z, w.z, az); aw = fmaf(h.w, w.w, aw);
    }
    h2sh[rr * 50 + j] = fmaxf(b2p[j] + (ax + ay) + (az + aw), 0.f);
  }
  __syncthreads();
  for (int idx = threadIdx.x; idx < 8 * 14; idx += 256) {
    int r2 = idx / 14;
    int j = idx - r2 * 14;
    float a0 = 0.f, a1 = 0.f;
    const float* h2 = &h2sh[r2 * 50];
    const float* wv = &W3[(size_t)j * 50];
#pragma unroll
    for (int k = 0; k < 25; ++k) {
      a0 = fmaf(h2[2*k],   wv[2*k],   a0);
      a1 = fmaf(h2[2*k+1], wv[2*k+1], a1);
    }
    out[(size_t)(base + r2) * 14 + j] = fmaxf(b3p[j] + a0 + a1, 0.f);
  }
}

// ---------------- launch ----------------

extern "C" void kernel_launch(void* const* d_in, const int* in_sizes, int n_in,
                              void* d_out, int out_size, void* d_ws, size_t ws_size,
                              hipStream_t stream) {
  (void)in_sizes; (void)n_in; (void)out_size; (void)ws_size;
  const float* x       = (const float*)d_in[0];
  const int*   lengths = (const int*)  d_in[1];
  const float* Wih     = (const float*)d_in[2];
  const float* Whh     = (const float*)d_in[3];
  const float* bih     = (const float*)d_in[4];
  const float* bhh     = (const float*)d_in[5];
  const float* W1      = (const float*)d_in[6];
  const float* b1      = (const float*)d_in[7];
  const float* W2      = (const float*)d_in[8];
  const float* b2      = (const float*)d_in[9];
  const float* W3      = (const float*)d_in[10];
  const float* b3      = (const float*)d_in[11];
  float* out = (float*)d_out;

  unsigned int* perm = (unsigned int*)d_ws;
  float* fbuf = (float*)(perm + NSEQ);

  sort_kernel<<<1, 1024, 0, stream>>>(lengths, perm);
  rnn_kernel<<<NSEQ / 32, 64, 0, stream>>>(x, lengths, Wih, Whh, bih, bhh, perm, fbuf);
  mlp_kernel<<<BB / 8, 256, 0, stream>>>(fbuf, W1, b1, W2, b2, W3, b3, out);
}

// Round 5
// 183.286 us; speedup vs baseline: 2.9384x; 1.5810x over previous
//
#include <hip/hip_runtime.h>
#include <stdint.h>

#define CC 6
#define BB 4096
#define TT 512
#define HH 26
#define NSEQ (CC*BB)      // 24576
#define FF (CC*HH)        // 156
#define NBIN (CC*TT)      // 3072

typedef _Float16 f16x8 __attribute__((ext_vector_type(8)));
typedef _Float16 f16x2 __attribute__((ext_vector_type(2)));
typedef float    f32x4 __attribute__((ext_vector_type(4)));
typedef int      i32x4 __attribute__((ext_vector_type(4)));

__device__ __forceinline__ float th(float a){   // tanh(z), z prescaled by 2*log2(e)
  return fmaf(-2.f, __builtin_amdgcn_rcpf(__builtin_amdgcn_exp2f(a) + 1.f), 1.f);
}
__device__ __forceinline__ int pkf16(float a, float b){
  return __builtin_bit_cast(int, __builtin_amdgcn_cvt_pkrtz(a, b));
}

// ---------------- counting sort (multi-block): key = c*512 + (512-len) ----------------

__global__ void zero_kernel(unsigned* __restrict__ hist, unsigned* __restrict__ curs) {
  int i = blockIdx.x * 256 + threadIdx.x;        // 12 blocks -> 3072
  hist[i] = 0u; curs[i] = 0u;
}

__global__ void hist_kernel(const int* __restrict__ lengths, unsigned* __restrict__ hist) {
  int s = blockIdx.x * 256 + threadIdx.x;        // 96 blocks
  int c = s >> 12, b = s & 4095;
  int len = lengths[b * CC + c];                 // 1..512
  atomicAdd(&hist[(c << 9) | (TT - len)], 1u);
}

__global__ __launch_bounds__(1024) void scan_kernel(const unsigned* __restrict__ hist,
                                                    unsigned* __restrict__ offs) {
  __shared__ unsigned tmp[1024];
  const int t = threadIdx.x;
  unsigned a0 = hist[3*t], a1 = hist[3*t+1], a2 = hist[3*t+2];
  unsigned ts = a0 + a1 + a2;
  tmp[t] = ts;
  __syncthreads();
  for (int d = 1; d < 1024; d <<= 1) {
    unsigned v = (t >= d) ? tmp[t - d] : 0u;
    __syncthreads();
    tmp[t] += v;
    __syncthreads();
  }
  unsigned excl = tmp[t] - ts;
  offs[3*t]   = excl;
  offs[3*t+1] = excl + a0;
  offs[3*t+2] = excl + a0 + a1;
}

__global__ void scatter_kernel(const int* __restrict__ lengths, const unsigned* __restrict__ offs,
                               unsigned* __restrict__ curs, unsigned* __restrict__ perm) {
  int s = blockIdx.x * 256 + threadIdx.x;        // 96 blocks
  int c = s >> 12, b = s & 4095;
  int len = lengths[b * CC + c];
  int bin = (c << 9) | (TT - len);
  unsigned p = atomicAdd(&curs[bin], 1u);
  perm[offs[bin] + p] = (unsigned)s;
}

// ---------------- RNN body: NS independent 16-seq MFMA streams, ZERO crossbar ----------------
// Fixed-point layout trick: A row-slot m holds W' row m (pi = id); A col-slot kappa = 8g+j
// samples W' column sigma(kappa) = 4g+j (j<4) | 16+4g+(j-4) (j>=4).
// Then D at lane (g,n) — rows {4g..4g+3} (D1) and {16+4g..+3} (D2) — IS the next B fragment:
//   b0,b1 = th(D1 pairs), b2,b3 = th(D2 pairs). No cross-lane movement at all.
// sigma = 26,27 (x cols) -> grp2's b3 slots; sigma = 28..31 (zero cols) -> grp3's b2,b3.
// Garbage D rows (26..31) are exactly the slots overwritten by x/0 -> self-consistent.

template<int NS>
__device__ __forceinline__ void rnn_body(
    int c, int chain0,
    const float* __restrict__ x, const int* __restrict__ lengths,
    const float* __restrict__ Wih, const float* __restrict__ Whh,
    const float* __restrict__ bih, const float* __restrict__ bhh,
    const unsigned* __restrict__ perm, float* __restrict__ fbuf)
{
  const int l = threadIdx.x, col = l & 15, grp = l >> 4;

  unsigned sid[NS]; int bi[NS]; int len[NS];
#pragma unroll
  for (int st = 0; st < NS; ++st) {
    sid[st] = perm[(chain0 + st) * 16 + col];
    bi[st]  = (int)(sid[st] & 4095u);
    len[st] = lengths[bi[st] * CC + c];
  }
  int ml = 0;
#pragma unroll
  for (int st = 0; st < NS; ++st) ml = ml > len[st] ? ml : len[st];
#pragma unroll
  for (int m = 8; m >= 1; m >>= 1) { int o = __shfl_xor(ml, m); ml = ml > o ? ml : o; }

  const float S = 2.0f * 1.44269504088896340736f;
  const float* WhhC = Whh + (size_t)c * HH * HH;
  const float* WihC = Wih + (size_t)c * HH * 2;

  f16x8 A1, A2;
#pragma unroll
  for (int j = 0; j < 8; ++j) {
    const int kk = (j < 4) ? (grp * 4 + j) : (12 + grp * 4 + j);  // sigma(8*grp+j)
    float v1 = (kk < HH) ? WhhC[col * HH + kk] : ((kk < HH + 2) ? WihC[col * 2 + (kk - HH)] : 0.f);
    A1[j] = (_Float16)(S * v1);
    const int m2 = 16 + col;
    float v2 = 0.f;
    if (m2 < HH) v2 = (kk < HH) ? WhhC[m2 * HH + kk] : ((kk < HH + 2) ? WihC[m2 * 2 + (kk - HH)] : 0.f);
    A2[j] = (_Float16)(S * v2);
  }
  f32x4 Cb1, Cb2;
#pragma unroll
  for (int i = 0; i < 4; ++i) {
    int m1 = grp * 4 + i;
    Cb1[i] = S * (bih[c * HH + m1] + bhh[c * HH + m1]);
    int m2 = 16 + grp * 4 + i;
    Cb2[i] = (m2 < HH) ? S * (bih[c * HH + m2] + bhh[c * HH + m2]) : 0.f;
  }

  int b0[NS], b1[NS], b2[NS], b3[NS];
#pragma unroll
  for (int st = 0; st < NS; ++st) { b0[st] = b1[st] = b2[st] = b3[st] = 0; }

  const bool isg2 = (grp == 2);
  const bool isg3 = (grp == 3);
  const float* xp[NS];
  float4 xa[NS], xb[NS];
#pragma unroll
  for (int st = 0; st < NS; ++st) {
    xp[st] = x + (size_t)sid[st] * (TT * 2);
    xa[st] = make_float4(0.f, 0.f, 0.f, 0.f); xb[st] = xa[st];
    if (isg2) {
      xa[st] = *(const float4*)(xp[st] + (TT - 4) * 2);
      xb[st] = *(const float4*)(xp[st] + (TT - 4) * 2 + 4);
    }
  }

  const int nch = (ml + 3) >> 2;
  for (int cc2 = 0; cc2 < nch; ++cc2) {
    float4 na[NS], nb[NS];
#pragma unroll
    for (int st = 0; st < NS; ++st) {
      na[st] = xa[st]; nb[st] = xb[st];
      if (isg2 && cc2 < 127) {
        const float* nx = xp[st] + (TT - 8 - 4 * cc2) * 2;
        na[st] = *(const float4*)nx;
        nb[st] = *(const float4*)(nx + 4);
      }
    }
#pragma unroll
    for (int j = 0; j < 4; ++j) {
      const int t = 4 * cc2 + j;
#pragma unroll
      for (int st = 0; st < NS; ++st) {
        float xf[8] = {xa[st].x, xa[st].y, xa[st].z, xa[st].w,
                       xb[st].x, xb[st].y, xb[st].z, xb[st].w};
        int px = pkf16(xf[(3 - j) * 2], xf[(3 - j) * 2 + 1]);   // (x0, x1) at step t
        int e2 = isg3 ? 0 : b2[st];
        int e3 = isg3 ? 0 : (isg2 ? px : b3[st]);
        i32x4 bv = {b0[st], b1[st], e2, e3};
        f16x8 B = __builtin_bit_cast(f16x8, bv);
        f32x4 D1 = __builtin_amdgcn_mfma_f32_16x16x32_f16(A1, B, Cb1, 0, 0, 0);
        f32x4 D2 = __builtin_amdgcn_mfma_f32_16x16x32_f16(A2, B, Cb2, 0, 0, 0);
        int n0 = pkf16(th(D1[0]), th(D1[1]));
        int n1 = pkf16(th(D1[2]), th(D1[3]));
        int n2 = pkf16(th(D2[0]), th(D2[1]));
        int n3 = pkf16(th(D2[2]), th(D2[3]));
        const bool upd = t < len[st];
        b0[st] = upd ? n0 : b0[st];
        b1[st] = upd ? n1 : b1[st];
        b2[st] = upd ? n2 : b2[st];
        b3[st] = upd ? n3 : b3[st];
      }
    }
#pragma unroll
    for (int st = 0; st < NS; ++st) { xa[st] = na[st]; xb[st] = nb[st]; }
  }

  // epilogue: lane (g,n) holds h[4g..4g+3] in b0,b1 and h[16+4g..16+4g+3] in b2,b3
  const int ma = grp * 4;
  const int mb = 16 + grp * 4;
#pragma unroll
  for (int st = 0; st < NS; ++st) {
    float* fb = fbuf + (size_t)bi[st] * FF + c * HH;
    f16x2 p;
    p = __builtin_bit_cast(f16x2, b0[st]);
    fb[25 - (ma + 0)] = fmaxf((float)p[0], 0.f);
    fb[25 - (ma + 1)] = fmaxf((float)p[1], 0.f);
    p = __builtin_bit_cast(f16x2, b1[st]);
    fb[25 - (ma + 2)] = fmaxf((float)p[0], 0.f);
    fb[25 - (ma + 3)] = fmaxf((float)p[1], 0.f);
    p = __builtin_bit_cast(f16x2, b2[st]);
    if (mb + 0 < HH) fb[25 - (mb + 0)] = fmaxf((float)p[0], 0.f);
    if (mb + 1 < HH) fb[25 - (mb + 1)] = fmaxf((float)p[1], 0.f);
    p = __builtin_bit_cast(f16x2, b3[st]);
    if (mb + 2 < HH) fb[25 - (mb + 2)] = fmaxf((float)p[0], 0.f);
    if (mb + 3 < HH) fb[25 - (mb + 3)] = fmaxf((float)p[1], 0.f);
  }
}

// hybrid schedule: per channel, 128 single-stream waves (longest chains) + 64 dual-stream waves
__global__ __launch_bounds__(64, 1) void rnn_kernel(
    const float* __restrict__ x, const int* __restrict__ lengths,
    const float* __restrict__ Wih, const float* __restrict__ Whh,
    const float* __restrict__ bih, const float* __restrict__ bhh,
    const unsigned* __restrict__ perm, float* __restrict__ fbuf)
{
  const int b = blockIdx.x;                      // 0..1151
  const int c = b / 192;
  const int r = b - c * 192;
  if (r < 128) {
    rnn_body<1>(c, c * 256 + r, x, lengths, Wih, Whh, bih, bhh, perm, fbuf);
  } else {
    rnn_body<2>(c, c * 256 + 128 + 2 * (r - 128), x, lengths, Wih, Whh, bih, bhh, perm, fbuf);
  }
}

// ---------------- fused 3-layer MLP: 4 rows/block, 1024 blocks ----------------

__global__ __launch_bounds__(256) void mlp_kernel(
    const float* __restrict__ fbuf,
    const float* __restrict__ W1, const float* __restrict__ b1p,
    const float* __restrict__ W2, const float* __restrict__ b2p,
    const float* __restrict__ W3, const float* __restrict__ b3p,
    float* __restrict__ out)
{
  __shared__ float fsh[4 * FF];
  __shared__ float h1sh[4 * 300];
  __shared__ float h2sh[4 * 50];
  const int base = blockIdx.x * 4;
  for (int i = threadIdx.x; i < 4 * FF; i += 256) fsh[i] = fbuf[(size_t)base * FF + i];
  __syncthreads();
  const int rr = threadIdx.x & 3;
  const int ch = threadIdx.x >> 2;               // 0..63
  const float4* frow = (const float4*)&fsh[rr * FF];
  for (int j = ch; j < 300; j += 64) {
    const float4* wrow = (const float4*)&W1[(size_t)j * FF];
    float ax = 0.f, ay = 0.f, az = 0.f, aw = 0.f;
#pragma unroll 13
    for (int k = 0; k < FF / 4; ++k) {
      float4 f = frow[k]; float4 w = wrow[k];
      ax = fmaf(f.x, w.x, ax); ay = fmaf(f.y, w.y, ay);
      az = fmaf(f.z, w.z, az); aw = fmaf(f.w, w.w, aw);
    }
    h1sh[rr * 300 + j] = fmaxf(b1p[j] + (ax + ay) + (az + aw), 0.f);
  }
  __syncthreads();
  const float4* hrow = (const float4*)&h1sh[rr * 300];
  for (int j = ch; j < 50; j += 64) {
    const float4* wrow = (const float4*)&W2[(size_t)j * 300];
    float ax = 0.f, ay = 0.f, az = 0.f, aw = 0.f;
#pragma unroll 15
    for (int k = 0; k < 75; ++k) {
      float4 h = hrow[k]; float4 w = wrow[k];
      ax = fmaf(h.x, w.x, ax); ay = fmaf(h.y, w.y, ay);
      az = fmaf(h.z, w.z, az); aw = fmaf(h.w, w.w, aw);
    }
    h2sh[rr * 50 + j] = fmaxf(b2p[j] + (ax + ay) + (az + aw), 0.f);
  }
  __syncthreads();
  for (int idx = threadIdx.x; idx < 4 * 14; idx += 256) {
    int r2 = idx / 14;
    int j = idx - r2 * 14;
    float a0 = 0.f, a1 = 0.f;
    const float* h2 = &h2sh[r2 * 50];
    const float* wv = &W3[(size_t)j * 50];
#pragma unroll
    for (int k = 0; k < 25; ++k) {
      a0 = fmaf(h2[2*k],   wv[2*k],   a0);
      a1 = fmaf(h2[2*k+1], wv[2*k+1], a1);
    }
    out[(size_t)(base + r2) * 14 + j] = fmaxf(b3p[j] + a0 + a1, 0.f);
  }
}

// ---------------- launch ----------------

extern "C" void kernel_launch(void* const* d_in, const int* in_sizes, int n_in,
                              void* d_out, int out_size, void* d_ws, size_t ws_size,
                              hipStream_t stream) {
  (void)in_sizes; (void)n_in; (void)out_size; (void)ws_size;
  const float* x       = (const float*)d_in[0];
  const int*   lengths = (const int*)  d_in[1];
  const float* Wih     = (const float*)d_in[2];
  const float* Whh     = (const float*)d_in[3];
  const float* bih     = (const float*)d_in[4];
  const float* bhh     = (const float*)d_in[5];
  const float* W1      = (const float*)d_in[6];
  const float* b1      = (const float*)d_in[7];
  const float* W2      = (const float*)d_in[8];
  const float* b2      = (const float*)d_in[9];
  const float* W3      = (const float*)d_in[10];
  const float* b3      = (const float*)d_in[11];
  float* out = (float*)d_out;

  unsigned* hist = (unsigned*)d_ws;
  unsigned* curs = hist + NBIN;
  unsigned* offs = curs + NBIN;
  unsigned* perm = offs + NBIN;
  float* fbuf = (float*)(perm + NSEQ);

  zero_kernel<<<NBIN / 256, 256, 0, stream>>>(hist, curs);
  hist_kernel<<<NSEQ / 256, 256, 0, stream>>>(lengths, hist);
  scan_kernel<<<1, 1024, 0, stream>>>(hist, offs);
  scatter_kernel<<<NSEQ / 256, 256, 0, stream>>>(lengths, offs, curs, perm);
  rnn_kernel<<<CC * 192, 64, 0, stream>>>(x, lengths, Wih, Whh, bih, bhh, perm, fbuf);
  mlp_kernel<<<BB / 4, 256, 0, stream>>>(fbuf, W1, b1, W2, b2, W3, b3, out);
}

// Round 6
// 145.559 us; speedup vs baseline: 3.7000x; 1.2592x over previous
//
#include <hip/hip_runtime.h>
#include <stdint.h>

#define CC 6
#define BB 4096
#define TT 512
#define HH 26
#define NSEQ (CC*BB)      // 24576
#define FF (CC*HH)        // 156
#define NBIN (CC*TT)      // 3072

typedef _Float16 f16x8 __attribute__((ext_vector_type(8)));
typedef _Float16 f16x2 __attribute__((ext_vector_type(2)));
typedef float    f32x4 __attribute__((ext_vector_type(4)));
typedef int      i32x4 __attribute__((ext_vector_type(4)));

__device__ __forceinline__ float th(float a){   // tanh(z), z prescaled by 2*log2(e)
  return fmaf(-2.f, __builtin_amdgcn_rcpf(__builtin_amdgcn_exp2f(a) + 1.f), 1.f);
}
__device__ __forceinline__ int pkf16(float a, float b){
  return __builtin_bit_cast(int, __builtin_amdgcn_cvt_pkrtz(a, b));
}

// ---------------- counting sort (multi-block): key = c*512 + (512-len) ----------------

__global__ void zero_kernel(unsigned* __restrict__ hist, unsigned* __restrict__ curs) {
  int i = blockIdx.x * 256 + threadIdx.x;        // 12 blocks -> 3072
  hist[i] = 0u; curs[i] = 0u;
}

__global__ void hist_kernel(const int* __restrict__ lengths, unsigned* __restrict__ hist) {
  int s = blockIdx.x * 256 + threadIdx.x;        // 96 blocks
  int c = s >> 12, b = s & 4095;
  int len = lengths[b * CC + c];                 // 1..512
  atomicAdd(&hist[(c << 9) | (TT - len)], 1u);
}

__global__ __launch_bounds__(1024) void scan_kernel(const unsigned* __restrict__ hist,
                                                    unsigned* __restrict__ offs) {
  __shared__ unsigned tmp[1024];
  const int t = threadIdx.x;
  unsigned a0 = hist[3*t], a1 = hist[3*t+1], a2 = hist[3*t+2];
  unsigned ts = a0 + a1 + a2;
  tmp[t] = ts;
  __syncthreads();
  for (int d = 1; d < 1024; d <<= 1) {
    unsigned v = (t >= d) ? tmp[t - d] : 0u;
    __syncthreads();
    tmp[t] += v;
    __syncthreads();
  }
  unsigned excl = tmp[t] - ts;
  offs[3*t]   = excl;
  offs[3*t+1] = excl + a0;
  offs[3*t+2] = excl + a0 + a1;
}

__global__ void scatter_kernel(const int* __restrict__ lengths, const unsigned* __restrict__ offs,
                               unsigned* __restrict__ curs, unsigned* __restrict__ perm) {
  int s = blockIdx.x * 256 + threadIdx.x;        // 96 blocks
  int c = s >> 12, b = s & 4095;
  int len = lengths[b * CC + c];
  int bin = (c << 9) | (TT - len);
  unsigned p = atomicAdd(&curs[bin], 1u);
  perm[offs[bin] + p] = (unsigned)s;
}

// ---------------- RNN: one wave = 16 same-channel sequences, zero-crossbar MFMA ----------------
// Fixed-point layout: A row-slot m holds W' row m; A col-slot kappa = 8g+j samples W' column
// sigma(kappa) = 4g+j (j<4) | 16+4g+(j-4) (j>=4). D at lane (g,n) — rows {4g..4g+3} (D1) and
// {16+4g..+3} (D2) — IS the next step's B fragment (b0,b1 = th(D1), b2,b3 = th(D2)).
// sigma = 26,27 (x cols) live in grp2's b3; sigma = 28..31 (zero) are grp3's b2,b3.
//
// Schedule: grid 1536, c = b % 6, rank = b / 6 (0 = longest chains first). Each CU's 6 waves
// get ranks spread ~43 apart -> per-CU work uniform (round-5 fix: same-rank pile-up on low CUs).

__global__ __launch_bounds__(64, 1) void rnn_kernel(
    const float* __restrict__ x, const int* __restrict__ lengths,
    const float* __restrict__ Wih, const float* __restrict__ Whh,
    const float* __restrict__ bih, const float* __restrict__ bhh,
    const unsigned* __restrict__ perm, float* __restrict__ fbuf)
{
  const int l = threadIdx.x, col = l & 15, grp = l >> 4;
  const int b = blockIdx.x;                      // 0..1535
  const int c = b % CC;
  const int rank = b / CC;                       // 0..255
  const int chain0 = c * 256 + rank;

  const unsigned sid = perm[chain0 * 16 + col];
  const int bi = (int)(sid & 4095u);
  const int len = lengths[bi * CC + c];

  int ml = len;
#pragma unroll
  for (int m = 8; m >= 1; m >>= 1) { int o = __shfl_xor(ml, m); ml = ml > o ? ml : o; }

  const float S = 2.0f * 1.44269504088896340736f;
  const float* WhhC = Whh + (size_t)c * HH * HH;
  const float* WihC = Wih + (size_t)c * HH * 2;

  f16x8 A1, A2;
#pragma unroll
  for (int j = 0; j < 8; ++j) {
    const int kk = (j < 4) ? (grp * 4 + j) : (12 + grp * 4 + j);  // sigma(8*grp+j)
    float v1 = (kk < HH) ? WhhC[col * HH + kk] : ((kk < HH + 2) ? WihC[col * 2 + (kk - HH)] : 0.f);
    A1[j] = (_Float16)(S * v1);
    const int m2 = 16 + col;
    float v2 = 0.f;
    if (m2 < HH) v2 = (kk < HH) ? WhhC[m2 * HH + kk] : ((kk < HH + 2) ? WihC[m2 * 2 + (kk - HH)] : 0.f);
    A2[j] = (_Float16)(S * v2);
  }
  f32x4 Cb1, Cb2;
#pragma unroll
  for (int i = 0; i < 4; ++i) {
    int m1 = grp * 4 + i;
    Cb1[i] = S * (bih[c * HH + m1] + bhh[c * HH + m1]);
    int m2 = 16 + grp * 4 + i;
    Cb2[i] = (m2 < HH) ? S * (bih[c * HH + m2] + bhh[c * HH + m2]) : 0.f;
  }

  int b0 = 0, b1 = 0, b2 = 0, b3 = 0;
  const bool isg2 = (grp == 2);
  const bool isg3 = (grp == 3);
  const float* xp = x + (size_t)sid * (TT * 2);

  // 8-step chunks, double-buffered: 4 x float4 = 16 floats = steps [TT-8-8*cc .. TT-1-8*cc]
  float4 X0 = make_float4(0,0,0,0), X1 = X0, X2 = X0, X3 = X0;
  if (isg2) {
    const float* p0 = xp + (TT - 8) * 2;
    X0 = *(const float4*)(p0 + 0);
    X1 = *(const float4*)(p0 + 4);
    X2 = *(const float4*)(p0 + 8);
    X3 = *(const float4*)(p0 + 12);
  }

  const int nch = (ml + 7) >> 3;
  for (int cc = 0; cc < nch; ++cc) {
    float4 N0 = X0, N1 = X1, N2 = X2, N3 = X3;
    if (isg2 && cc < 63) {
      const float* pn = xp + (TT - 16 - 8 * cc) * 2;
      N0 = *(const float4*)(pn + 0);
      N1 = *(const float4*)(pn + 4);
      N2 = *(const float4*)(pn + 8);
      N3 = *(const float4*)(pn + 12);
    }
    const float xq[16] = {X0.x, X0.y, X0.z, X0.w, X1.x, X1.y, X1.z, X1.w,
                          X2.x, X2.y, X2.z, X2.w, X3.x, X3.y, X3.z, X3.w};
#pragma unroll
    for (int j = 0; j < 8; ++j) {
      const int t = 8 * cc + j;
      int px = pkf16(xq[(7 - j) * 2], xq[(7 - j) * 2 + 1]);   // (x0, x1) at step t
      int e2 = isg3 ? 0 : b2;
      int e3 = isg3 ? 0 : (isg2 ? px : b3);
      i32x4 bv = {b0, b1, e2, e3};
      f16x8 B = __builtin_bit_cast(f16x8, bv);
      f32x4 D1 = __builtin_amdgcn_mfma_f32_16x16x32_f16(A1, B, Cb1, 0, 0, 0);
      f32x4 D2 = __builtin_amdgcn_mfma_f32_16x16x32_f16(A2, B, Cb2, 0, 0, 0);
      int n0 = pkf16(th(D1[0]), th(D1[1]));
      int n1 = pkf16(th(D1[2]), th(D1[3]));
      int n2 = pkf16(th(D2[0]), th(D2[1]));
      int n3 = pkf16(th(D2[2]), th(D2[3]));
      const bool upd = t < len;
      b0 = upd ? n0 : b0;
      b1 = upd ? n1 : b1;
      b2 = upd ? n2 : b2;
      b3 = upd ? n3 : b3;
    }
    X0 = N0; X1 = N1; X2 = N2; X3 = N3;
  }

  // epilogue: lane (g,n) holds h[4g..4g+3] in b0,b1 and h[16+4g..16+4g+3] in b2,b3
  const int ma = grp * 4;
  const int mb = 16 + grp * 4;
  float* fb = fbuf + (size_t)bi * FF + c * HH;
  f16x2 p;
  p = __builtin_bit_cast(f16x2, b0);
  fb[25 - (ma + 0)] = fmaxf((float)p[0], 0.f);
  fb[25 - (ma + 1)] = fmaxf((float)p[1], 0.f);
  p = __builtin_bit_cast(f16x2, b1);
  fb[25 - (ma + 2)] = fmaxf((float)p[0], 0.f);
  fb[25 - (ma + 3)] = fmaxf((float)p[1], 0.f);
  p = __builtin_bit_cast(f16x2, b2);
  if (mb + 0 < HH) fb[25 - (mb + 0)] = fmaxf((float)p[0], 0.f);
  if (mb + 1 < HH) fb[25 - (mb + 1)] = fmaxf((float)p[1], 0.f);
  p = __builtin_bit_cast(f16x2, b3);
  if (mb + 2 < HH) fb[25 - (mb + 2)] = fmaxf((float)p[0], 0.f);
  if (mb + 3 < HH) fb[25 - (mb + 3)] = fmaxf((float)p[1], 0.f);
}

// ---------------- fused 3-layer MLP: 4 rows/block, 1024 blocks ----------------

__global__ __launch_bounds__(256) void mlp_kernel(
    const float* __restrict__ fbuf,
    const float* __restrict__ W1, const float* __restrict__ b1p,
    const float* __restrict__ W2, const float* __restrict__ b2p,
    const float* __restrict__ W3, const float* __restrict__ b3p,
    float* __restrict__ out)
{
  __shared__ float fsh[4 * FF];
  __shared__ float h1sh[4 * 300];
  __shared__ float h2sh[4 * 50];
  const int base = blockIdx.x * 4;
  for (int i = threadIdx.x; i < 4 * FF; i += 256) fsh[i] = fbuf[(size_t)base * FF + i];
  __syncthreads();
  const int rr = threadIdx.x & 3;
  const int ch = threadIdx.x >> 2;               // 0..63
  const float4* frow = (const float4*)&fsh[rr * FF];
  for (int j = ch; j < 300; j += 64) {
    const float4* wrow = (const float4*)&W1[(size_t)j * FF];
    float ax = 0.f, ay = 0.f, az = 0.f, aw = 0.f;
#pragma unroll 13
    for (int k = 0; k < FF / 4; ++k) {
      float4 f = frow[k]; float4 w = wrow[k];
      ax = fmaf(f.x, w.x, ax); ay = fmaf(f.y, w.y, ay);
      az = fmaf(f.z, w.z, az); aw = fmaf(f.w, w.w, aw);
    }
    h1sh[rr * 300 + j] = fmaxf(b1p[j] + (ax + ay) + (az + aw), 0.f);
  }
  __syncthreads();
  const float4* hrow = (const float4*)&h1sh[rr * 300];
  for (int j = ch; j < 50; j += 64) {
    const float4* wrow = (const float4*)&W2[(size_t)j * 300];
    float ax = 0.f, ay = 0.f, az = 0.f, aw = 0.f;
#pragma unroll 15
    for (int k = 0; k < 75; ++k) {
      float4 h = hrow[k]; float4 w = wrow[k];
      ax = fmaf(h.x, w.x, ax); ay = fmaf(h.y, w.y, ay);
      az = fmaf(h.z, w.z, az); aw = fmaf(h.w, w.w, aw);
    }
    h2sh[rr * 50 + j] = fmaxf(b2p[j] + (ax + ay) + (az + aw), 0.f);
  }
  __syncthreads();
  for (int idx = threadIdx.x; idx < 4 * 14; idx += 256) {
    int r2 = idx / 14;
    int j = idx - r2 * 14;
    float a0 = 0.f, a1 = 0.f;
    const float* h2 = &h2sh[r2 * 50];
    const float* wv = &W3[(size_t)j * 50];
#pragma unroll
    for (int k = 0; k < 25; ++k) {
      a0 = fmaf(h2[2*k],   wv[2*k],   a0);
      a1 = fmaf(h2[2*k+1], wv[2*k+1], a1);
    }
    out[(size_t)(base + r2) * 14 + j] = fmaxf(b3p[j] + a0 + a1, 0.f);
  }
}

// ---------------- launch ----------------

extern "C" void kernel_launch(void* const* d_in, const int* in_sizes, int n_in,
                              void* d_out, int out_size, void* d_ws, size_t ws_size,
                              hipStream_t stream) {
  (void)in_sizes; (void)n_in; (void)out_size; (void)ws_size;
  const float* x       = (const float*)d_in[0];
  const int*   lengths = (const int*)  d_in[1];
  const float* Wih     = (const float*)d_in[2];
  const float* Whh     = (const float*)d_in[3];
  const float* bih     = (const float*)d_in[4];
  const float* bhh     = (const float*)d_in[5];
  const float* W1      = (const float*)d_in[6];
  const float* b1      = (const float*)d_in[7];
  const float* W2      = (const float*)d_in[8];
  const float* b2      = (const float*)d_in[9];
  const float* W3      = (const float*)d_in[10];
  const float* b3      = (const float*)d_in[11];
  float* out = (float*)d_out;

  unsigned* hist = (unsigned*)d_ws;
  unsigned* curs = hist + NBIN;
  unsigned* offs = curs + NBIN;
  unsigned* perm = offs + NBIN;
  float* fbuf = (float*)(perm + NSEQ);

  zero_kernel<<<NBIN / 256, 256, 0, stream>>>(hist, curs);
  hist_kernel<<<NSEQ / 256, 256, 0, stream>>>(lengths, hist);
  scan_kernel<<<1, 1024, 0, stream>>>(hist, offs);
  scatter_kernel<<<NSEQ / 256, 256, 0, stream>>>(lengths, offs, curs, perm);
  rnn_kernel<<<CC * 256, 64, 0, stream>>>(x, lengths, Wih, Whh, bih, bhh, perm, fbuf);
  mlp_kernel<<<BB / 4, 256, 0, stream>>>(fbuf, W1, b1, W2, b2, W3, b3, out);
}

// Round 7
// 135.021 us; speedup vs baseline: 3.9888x; 1.0781x over previous
//
#include <hip/hip_runtime.h>
#include <stdint.h>

#define CC 6
#define BB 4096
#define TT 512
#define HH 26
#define NSEQ (CC*BB)      // 24576
#define FF (CC*HH)        // 156
#define NBIN (CC*TT)      // 3072

typedef _Float16 f16x8 __attribute__((ext_vector_type(8)));
typedef _Float16 f16x2 __attribute__((ext_vector_type(2)));
typedef float    f32x4 __attribute__((ext_vector_type(4)));
typedef int      i32x4 __attribute__((ext_vector_type(4)));

__device__ __forceinline__ float th(float a){   // tanh(z), z prescaled by 2*log2(e)
  return fmaf(-2.f, __builtin_amdgcn_rcpf(__builtin_amdgcn_exp2f(a) + 1.f), 1.f);
}
__device__ __forceinline__ int pkf16(float a, float b){
  return __builtin_bit_cast(int, __builtin_amdgcn_cvt_pkrtz(a, b));
}

// ---------------- counting sort (multi-block): key = c*512 + (512-len) ----------------

__global__ void hist_kernel(const int* __restrict__ lengths, unsigned* __restrict__ hist) {
  int s = blockIdx.x * 256 + threadIdx.x;        // 96 blocks
  int c = s >> 12, b = s & 4095;
  int len = lengths[b * CC + c];                 // 1..512
  atomicAdd(&hist[(c << 9) | (TT - len)], 1u);
}

__global__ __launch_bounds__(1024) void scan_kernel(const unsigned* __restrict__ hist,
                                                    unsigned* __restrict__ offs) {
  __shared__ unsigned tmp[1024];
  const int t = threadIdx.x;
  unsigned a0 = hist[3*t], a1 = hist[3*t+1], a2 = hist[3*t+2];
  unsigned ts = a0 + a1 + a2;
  tmp[t] = ts;
  __syncthreads();
  for (int d = 1; d < 1024; d <<= 1) {
    unsigned v = (t >= d) ? tmp[t - d] : 0u;
    __syncthreads();
    tmp[t] += v;
    __syncthreads();
  }
  unsigned excl = tmp[t] - ts;
  offs[3*t]   = excl;
  offs[3*t+1] = excl + a0;
  offs[3*t+2] = excl + a0 + a1;
}

__global__ void scatter_kernel(const int* __restrict__ lengths, const unsigned* __restrict__ offs,
                               unsigned* __restrict__ curs, unsigned* __restrict__ perm) {
  int s = blockIdx.x * 256 + threadIdx.x;        // 96 blocks
  int c = s >> 12, b = s & 4095;
  int len = lengths[b * CC + c];
  int bin = (c << 9) | (TT - len);
  unsigned p = atomicAdd(&curs[bin], 1u);
  perm[offs[bin] + p] = (unsigned)s;
}

// ---------------- RNN: one wave = 16 same-channel sequences, zero-crossbar MFMA ----------------
// Fixed-point layout: A row-slot m holds W' row m; A col-slot kappa = 8g+j samples W' column
// sigma(kappa) = 4g+j (j<4) | 16+4g+(j-4) (j>=4). D at lane (g,n) — rows {4g..4g+3} (D1) and
// {16+4g..+3} (D2) — IS the next step's B fragment (b0,b1 = th(D1), b2,b3 = th(D2)).
// sigma = 26,27 (x cols) live in grp2's b3; sigma = 28..31 (zero) are grp3's b2,b3.

__device__ __forceinline__ void rnn_chain(
    int c, int rank,
    const float* __restrict__ x, const int* __restrict__ lengths,
    const float* __restrict__ Wih, const float* __restrict__ Whh,
    const float* __restrict__ bih, const float* __restrict__ bhh,
    const unsigned* __restrict__ perm, float* __restrict__ fbuf)
{
  const int l = threadIdx.x & 63, col = l & 15, grp = l >> 4;
  const int chain0 = c * 256 + rank;

  const unsigned sid = perm[chain0 * 16 + col];
  const int bi = (int)(sid & 4095u);
  const int len = lengths[bi * CC + c];

  int ml = len;
#pragma unroll
  for (int m = 8; m >= 1; m >>= 1) { int o = __shfl_xor(ml, m); ml = ml > o ? ml : o; }

  const float S = 2.0f * 1.44269504088896340736f;
  const float* WhhC = Whh + (size_t)c * HH * HH;
  const float* WihC = Wih + (size_t)c * HH * 2;

  f16x8 A1, A2;
#pragma unroll
  for (int j = 0; j < 8; ++j) {
    const int kk = (j < 4) ? (grp * 4 + j) : (12 + grp * 4 + j);  // sigma(8*grp+j)
    float v1 = (kk < HH) ? WhhC[col * HH + kk] : ((kk < HH + 2) ? WihC[col * 2 + (kk - HH)] : 0.f);
    A1[j] = (_Float16)(S * v1);
    const int m2 = 16 + col;
    float v2 = 0.f;
    if (m2 < HH) v2 = (kk < HH) ? WhhC[m2 * HH + kk] : ((kk < HH + 2) ? WihC[m2 * 2 + (kk - HH)] : 0.f);
    A2[j] = (_Float16)(S * v2);
  }
  f32x4 Cb1, Cb2;
#pragma unroll
  for (int i = 0; i < 4; ++i) {
    int m1 = grp * 4 + i;
    Cb1[i] = S * (bih[c * HH + m1] + bhh[c * HH + m1]);
    int m2 = 16 + grp * 4 + i;
    Cb2[i] = (m2 < HH) ? S * (bih[c * HH + m2] + bhh[c * HH + m2]) : 0.f;
  }

  int b0 = 0, b1 = 0, b2 = 0, b3 = 0;
  const bool isg2 = (grp == 2);
  const bool isg3 = (grp == 3);
  const float* xp = x + (size_t)sid * (TT * 2);

  // 8-step chunks, double-buffered: 4 x float4 = 16 floats = steps [TT-8-8*cc .. TT-1-8*cc]
  float4 X0 = make_float4(0,0,0,0), X1 = X0, X2 = X0, X3 = X0;
  if (isg2) {
    const float* p0 = xp + (TT - 8) * 2;
    X0 = *(const float4*)(p0 + 0);
    X1 = *(const float4*)(p0 + 4);
    X2 = *(const float4*)(p0 + 8);
    X3 = *(const float4*)(p0 + 12);
  }

  const int nch = (ml + 7) >> 3;
  for (int cc = 0; cc < nch; ++cc) {
    float4 N0 = X0, N1 = X1, N2 = X2, N3 = X3;
    if (isg2 && cc < 63) {
      const float* pn = xp + (TT - 16 - 8 * cc) * 2;
      N0 = *(const float4*)(pn + 0);
      N1 = *(const float4*)(pn + 4);
      N2 = *(const float4*)(pn + 8);
      N3 = *(const float4*)(pn + 12);
    }
    const float xq[16] = {X0.x, X0.y, X0.z, X0.w, X1.x, X1.y, X1.z, X1.w,
                          X2.x, X2.y, X2.z, X2.w, X3.x, X3.y, X3.z, X3.w};
#pragma unroll
    for (int j = 0; j < 8; ++j) {
      const int t = 8 * cc + j;
      int px = pkf16(xq[(7 - j) * 2], xq[(7 - j) * 2 + 1]);   // (x0, x1) at step t
      int e2 = isg3 ? 0 : b2;
      int e3 = isg3 ? 0 : (isg2 ? px : b3);
      i32x4 bv = {b0, b1, e2, e3};
      f16x8 B = __builtin_bit_cast(f16x8, bv);
      f32x4 D1 = __builtin_amdgcn_mfma_f32_16x16x32_f16(A1, B, Cb1, 0, 0, 0);
      f32x4 D2 = __builtin_amdgcn_mfma_f32_16x16x32_f16(A2, B, Cb2, 0, 0, 0);
      int n0 = pkf16(th(D1[0]), th(D1[1]));
      int n1 = pkf16(th(D1[2]), th(D1[3]));
      int n2 = pkf16(th(D2[0]), th(D2[1]));
      int n3 = pkf16(th(D2[2]), th(D2[3]));
      const bool upd = t < len;
      b0 = upd ? n0 : b0;
      b1 = upd ? n1 : b1;
      b2 = upd ? n2 : b2;
      b3 = upd ? n3 : b3;
    }
    X0 = N0; X1 = N1; X2 = N2; X3 = N3;
  }

  // epilogue: lane (g,n) holds h[4g..4g+3] in b0,b1 and h[16+4g..16+4g+3] in b2,b3
  const int ma = grp * 4;
  const int mb = 16 + grp * 4;
  float* fb = fbuf + (size_t)bi * FF + c * HH;
  f16x2 p;
  p = __builtin_bit_cast(f16x2, b0);
  fb[25 - (ma + 0)] = fmaxf((float)p[0], 0.f);
  fb[25 - (ma + 1)] = fmaxf((float)p[1], 0.f);
  p = __builtin_bit_cast(f16x2, b1);
  fb[25 - (ma + 2)] = fmaxf((float)p[0], 0.f);
  fb[25 - (ma + 3)] = fmaxf((float)p[1], 0.f);
  p = __builtin_bit_cast(f16x2, b2);
  if (mb + 0 < HH) fb[25 - (mb + 0)] = fmaxf((float)p[0], 0.f);
  if (mb + 1 < HH) fb[25 - (mb + 1)] = fmaxf((float)p[1], 0.f);
  p = __builtin_bit_cast(f16x2, b3);
  if (mb + 2 < HH) fb[25 - (mb + 2)] = fmaxf((float)p[0], 0.f);
  if (mb + 3 < HH) fb[25 - (mb + 3)] = fmaxf((float)p[1], 0.f);
}

// Static queue schedule, placement-proof: 256 blocks x 256 threads -> 1 block/CU, and the
// block's 4 waves land on the CU's 4 SIMDs -> every wave is issue-solo.
// Wave w (0..1023): w < 512 -> solo chain w (longest, 512..~342 steps).
//                   w >= 512 -> chains {w, 2047-w} back-to-back (len sum ~= 342 steps const).
// Chain g -> rank = g/6 (descending length), c = g%6.

__global__ __launch_bounds__(256, 1) void rnn_kernel(
    const float* __restrict__ x, const int* __restrict__ lengths,
    const float* __restrict__ Wih, const float* __restrict__ Whh,
    const float* __restrict__ bih, const float* __restrict__ bhh,
    const unsigned* __restrict__ perm, float* __restrict__ fbuf)
{
  const int w = blockIdx.x * 4 + (threadIdx.x >> 6);   // 0..1023
  if (w < 512) {
    rnn_chain(w % CC, w / CC, x, lengths, Wih, Whh, bih, bhh, perm, fbuf);
  } else {
    const int g1 = w;
    const int g2 = 2047 - w;
    rnn_chain(g1 % CC, g1 / CC, x, lengths, Wih, Whh, bih, bhh, perm, fbuf);
    rnn_chain(g2 % CC, g2 / CC, x, lengths, Wih, Whh, bih, bhh, perm, fbuf);
  }
}

// ---------------- fused 3-layer MLP: 4 rows/block, 1024 blocks ----------------

__global__ __launch_bounds__(256) void mlp_kernel(
    const float* __restrict__ fbuf,
    const float* __restrict__ W1, const float* __restrict__ b1p,
    const float* __restrict__ W2, const float* __restrict__ b2p,
    const float* __restrict__ W3, const float* __restrict__ b3p,
    float* __restrict__ out)
{
  __shared__ float fsh[4 * FF];
  __shared__ float h1sh[4 * 300];
  __shared__ float h2sh[4 * 50];
  const int base = blockIdx.x * 4;
  for (int i = threadIdx.x; i < 4 * FF; i += 256) fsh[i] = fbuf[(size_t)base * FF + i];
  __syncthreads();
  const int rr = threadIdx.x & 3;
  const int ch = threadIdx.x >> 2;               // 0..63
  const float4* frow = (const float4*)&fsh[rr * FF];
  for (int j = ch; j < 300; j += 64) {
    const float4* wrow = (const float4*)&W1[(size_t)j * FF];
    float ax = 0.f, ay = 0.f, az = 0.f, aw = 0.f;
#pragma unroll 13
    for (int k = 0; k < FF / 4; ++k) {
      float4 f = frow[k]; float4 w = wrow[k];
      ax = fmaf(f.x, w.x, ax); ay = fmaf(f.y, w.y, ay);
      az = fmaf(f.z, w.z, az); aw = fmaf(f.w, w.w, aw);
    }
    h1sh[rr * 300 + j] = fmaxf(b1p[j] + (ax + ay) + (az + aw), 0.f);
  }
  __syncthreads();
  const float4* hrow = (const float4*)&h1sh[rr * 300];
  for (int j = ch; j < 50; j += 64) {
    const float4* wrow = (const float4*)&W2[(size_t)j * 300];
    float ax = 0.f, ay = 0.f, az = 0.f, aw = 0.f;
#pragma unroll 15
    for (int k = 0; k < 75; ++k) {
      float4 h = hrow[k]; float4 w = wrow[k];
      ax = fmaf(h.x, w.x, ax); ay = fmaf(h.y, w.y, ay);
      az = fmaf(h.z, w.z, az); aw = fmaf(h.w, w.w, aw);
    }
    h2sh[rr * 50 + j] = fmaxf(b2p[j] + (ax + ay) + (az + aw), 0.f);
  }
  __syncthreads();
  for (int idx = threadIdx.x; idx < 4 * 14; idx += 256) {
    int r2 = idx / 14;
    int j = idx - r2 * 14;
    float a0 = 0.f, a1 = 0.f;
    const float* h2 = &h2sh[r2 * 50];
    const float* wv = &W3[(size_t)j * 50];
#pragma unroll
    for (int k = 0; k < 25; ++k) {
      a0 = fmaf(h2[2*k],   wv[2*k],   a0);
      a1 = fmaf(h2[2*k+1], wv[2*k+1], a1);
    }
    out[(size_t)(base + r2) * 14 + j] = fmaxf(b3p[j] + a0 + a1, 0.f);
  }
}

// ---------------- launch ----------------

extern "C" void kernel_launch(void* const* d_in, const int* in_sizes, int n_in,
                              void* d_out, int out_size, void* d_ws, size_t ws_size,
                              hipStream_t stream) {
  (void)in_sizes; (void)n_in; (void)out_size; (void)ws_size;
  const float* x       = (const float*)d_in[0];
  const int*   lengths = (const int*)  d_in[1];
  const float* Wih     = (const float*)d_in[2];
  const float* Whh     = (const float*)d_in[3];
  const float* bih     = (const float*)d_in[4];
  const float* bhh     = (const float*)d_in[5];
  const float* W1      = (const float*)d_in[6];
  const float* b1      = (const float*)d_in[7];
  const float* W2      = (const float*)d_in[8];
  const float* b2      = (const float*)d_in[9];
  const float* W3      = (const float*)d_in[10];
  const float* b3      = (const float*)d_in[11];
  float* out = (float*)d_out;

  unsigned* hist = (unsigned*)d_ws;
  unsigned* curs = hist + NBIN;
  unsigned* offs = curs + NBIN;
  unsigned* perm = offs + NBIN;
  float* fbuf = (float*)(perm + NSEQ);

  hipMemsetAsync(hist, 0, 2 * NBIN * sizeof(unsigned), stream);   // hist + curs
  hist_kernel<<<NSEQ / 256, 256, 0, stream>>>(lengths, hist);
  scan_kernel<<<1, 1024, 0, stream>>>(hist, offs);
  scatter_kernel<<<NSEQ / 256, 256, 0, stream>>>(lengths, offs, curs, perm);
  rnn_kernel<<<256, 256, 0, stream>>>(x, lengths, Wih, Whh, bih, bhh, perm, fbuf);
  mlp_kernel<<<BB / 4, 256, 0, stream>>>(fbuf, W1, b1, W2, b2, W3, b3, out);
}